// Round 22
// baseline (170.103 us; speedup 1.0000x reference)
//
#include <hip/hip_runtime.h>

typedef _Float16 half_t;
typedef __attribute__((ext_vector_type(8))) _Float16 half8;
typedef __attribute__((ext_vector_type(4))) _Float16 half4;
typedef __attribute__((ext_vector_type(4))) float f32x4;

#define SEQ   2048
#define DM    1024
#define NH    16
#define DEPTH 64

__device__ __forceinline__ void gload16(const void* g, void* l) {
    __builtin_amdgcn_global_load_lds(
        (const __attribute__((address_space(1))) void*)g,
        (__attribute__((address_space(3))) void*)l, 16, 0, 0);
}

// ---------------- weight transpose + fp32->fp16  AND  mask compaction ----------------
__global__ __launch_bounds__(256) void wm_k(
    const float* __restrict__ w0, const float* __restrict__ w1,
    const float* __restrict__ w2, const float* __restrict__ w3,
    half_t* __restrict__ out,
    const int* __restrict__ mask, int* __restrict__ idx, int* __restrict__ cnt)
{
    const int z = blockIdx.z;
    if (z == 4) {
        if (blockIdx.x || blockIdx.y) return;
        const int tid = threadIdx.y * 32 + threadIdx.x;
        const int b = tid >> 6;
        const int lane = tid & 63;
        const int* m = mask + b*SEQ;
        int* ib = idx + b*SEQ;
        int off = 0;
        for (int c = 0; c < SEQ; c += 64) {
            int keep = (m[c + lane] == 0);
            unsigned long long bal = __ballot(keep);
            int pre = __popcll(bal & ((1ull << lane) - 1ull));
            if (keep) ib[off + pre] = c + lane;
            off += __popcll(bal);
        }
        if (lane == 0) cnt[b] = off;
        return;
    }
    __shared__ float tile[32][33];
    const float* srcs[4] = {w0, w1, w2, w3};
    const float* src = srcs[z];
    half_t* dst = out + (size_t)z * DM * DM;
    int n0 = blockIdx.x * 32, k0 = blockIdx.y * 32;
    int tx = threadIdx.x, ty = threadIdx.y;
#pragma unroll
    for (int i = 0; i < 4; ++i)
        tile[ty + 8*i][tx] = src[(size_t)(k0 + ty + 8*i)*DM + n0 + tx];
    __syncthreads();
#pragma unroll
    for (int i = 0; i < 4; ++i)
        dst[(size_t)(n0 + ty + 8*i)*DM + k0 + tx] = (half_t)tile[tx][ty + 8*i];
}

// ---------------- q convert + k/v gather-convert, one launch ----------------
__global__ __launch_bounds__(256) void cvt3_k(
    const float* __restrict__ qsrc, const float* __restrict__ ksrc,
    const float* __restrict__ vsrc,
    const int* __restrict__ idx, const int* __restrict__ cnt,
    half_t* __restrict__ qdst, half_t* __restrict__ kdst, half_t* __restrict__ vdst)
{
    const int bid = blockIdx.x;
    const int t = threadIdx.x;
    if (bid < 4096) {
        size_t i = ((size_t)bid * 256 + t) * 8;
        float4 a = *(const float4*)(qsrc + i);
        float4 b = *(const float4*)(qsrc + i + 4);
        half8 h;
        h[0]=(half_t)a.x; h[1]=(half_t)a.y; h[2]=(half_t)a.z; h[3]=(half_t)a.w;
        h[4]=(half_t)b.x; h[5]=(half_t)b.y; h[6]=(half_t)b.z; h[7]=(half_t)b.w;
        *(half8*)(qdst + i) = h;
        return;
    }
    const int which = (bid >= 4608);
    const float* src = which ? vsrc : ksrc;
    half_t*      dst = which ? vdst : kdst;
    const int r0 = (bid - (which ? 4608 : 4096)) * 16;
    const int b  = r0 >> 11;
    const int nc = cnt[b];
    const int row = r0 + (t >> 4);
    const int jl  = row & (SEQ - 1);
    if (jl >= nc) return;
    const float* sp = src + (size_t)((b << 11) + idx[(b << 11) + jl]) * DM;
    half_t* dp = dst + (size_t)row * DM;
#pragma unroll
    for (int i = 0; i < 8; ++i) {
        int c = i*128 + (t & 15)*8;
        float4 lo = *(const float4*)(sp + c);
        float4 hi = *(const float4*)(sp + c + 4);
        half8 h;
        h[0]=(half_t)lo.x; h[1]=(half_t)lo.y; h[2]=(half_t)lo.z; h[3]=(half_t)lo.w;
        h[4]=(half_t)hi.x; h[5]=(half_t)hi.y; h[6]=(half_t)hi.z; h[7]=(half_t)hi.w;
        *(half8*)(dp + c) = h;
    }
}

// LDS XOR-swizzle (T2, rule #21): LDS[r][s] holds global slot s^(r&7).

// ---------------- merged Q+K deep-pipelined projection (512 blocks, z-decode) ----------------
__global__ __launch_bounds__(512, 2) void qk8_k(
    const half_t* __restrict__ Aq, const half_t* __restrict__ Ak,
    const half_t* __restrict__ wT,
    const float* __restrict__ bq, const float* __restrict__ bk,
    float qscale,
    half_t* __restrict__ Qh, half_t* __restrict__ Kc)
{
    __shared__ __align__(16) half_t smem[3 * 24576];
    const int flat = blockIdx.x;                 // 0..511
    const int wg   = (flat & 7) * 64 + (flat >> 3);
    const int z    = wg >> 8;                    // 0=Q, 1=K
    const int rem  = wg & 255;
    const int n0   = (rem & 3) * 256;
    const int m0   = (rem >> 2) * 128;

    const half_t* A    = z ? Ak : Aq;
    const half_t* Bt   = wT + (size_t)z * DM * DM;
    const float*  bias = z ? bk : bq;
    half_t*       Cp   = z ? Kc : Qh;
    const float   os   = z ? 1.0f : qscale;

    const int t = threadIdx.x, lane = t & 63, wave = t >> 6;
    const int wr = wave >> 2, wc = wave & 3;
    const int lr = lane & 15, lq = lane >> 4;
    const int l7 = lr & 7;

    f32x4 acc[4][4] = {};

#pragma unroll
    for (int kt = 0; kt < 2; ++kt) {
#pragma unroll
        for (int i = 0; i < 2; ++i) {
            int c = i*512 + t, r = c>>3, s = c&7;
            gload16(A + (size_t)(m0 + r)*DM + kt*64 + (s ^ (r&7))*8,
                    smem + kt*24576 + c*8);
        }
#pragma unroll
        for (int i = 0; i < 4; ++i) {
            int c = i*512 + t, r = c>>3, s = c&7;
            gload16(Bt + (size_t)(n0 + r)*DM + kt*64 + (s ^ (r&7))*8,
                    smem + kt*24576 + 8192 + c*8);
        }
    }
    asm volatile("s_waitcnt vmcnt(6)" ::: "memory");
    __builtin_amdgcn_s_barrier();

    for (int kt = 0; kt < 16; ++kt) {
        const int cur = kt % 3;
        const half_t* lA = smem + cur*24576;
        const half_t* lB = smem + cur*24576 + 8192;

        // issue next-next tile staging FIRST (overlaps ds_reads and MFMA)
        if (kt + 2 < 16) {
            const int nxt = (kt + 2) % 3;
            const int kn = kt + 2;
#pragma unroll
            for (int i = 0; i < 2; ++i) {
                int c = i*512 + t, r = c>>3, s = c&7;
                gload16(A + (size_t)(m0 + r)*DM + kn*64 + (s ^ (r&7))*8,
                        smem + nxt*24576 + c*8);
            }
#pragma unroll
            for (int i = 0; i < 4; ++i) {
                int c = i*512 + t, r = c>>3, s = c&7;
                gload16(Bt + (size_t)(n0 + r)*DM + kn*64 + (s ^ (r&7))*8,
                        smem + nxt*24576 + 8192 + c*8);
            }
        }

        half8 af[4][2], bf[4][2];
#pragma unroll
        for (int mi = 0; mi < 4; ++mi)
#pragma unroll
            for (int kk = 0; kk < 2; ++kk)
                af[mi][kk] = *(const half8*)(lA + (wr*64 + mi*16 + lr)*64 + (((kk*4+lq) ^ l7))*8);
#pragma unroll
        for (int ni = 0; ni < 4; ++ni)
#pragma unroll
            for (int kk = 0; kk < 2; ++kk)
                bf[ni][kk] = *(const half8*)(lB + (wc*64 + ni*16 + lr)*64 + (((kk*4+lq) ^ l7))*8);

        __builtin_amdgcn_s_setprio(1);
#pragma unroll
        for (int mi = 0; mi < 4; ++mi)
#pragma unroll
            for (int ni = 0; ni < 4; ++ni)
#pragma unroll
                for (int kk = 0; kk < 2; ++kk)
                    acc[mi][ni] = __builtin_amdgcn_mfma_f32_16x16x32_f16(af[mi][kk], bf[ni][kk], acc[mi][ni], 0, 0, 0);
        __builtin_amdgcn_s_setprio(0);

        if (kt < 15) {
            if (kt < 14) asm volatile("s_waitcnt vmcnt(6)" ::: "memory");
            else         asm volatile("s_waitcnt vmcnt(0)" ::: "memory");
            __builtin_amdgcn_s_barrier();
        }
    }

#pragma unroll
    for (int mi = 0; mi < 4; ++mi) {
#pragma unroll
        for (int ni = 0; ni < 4; ++ni) {
            int col = n0 + wc*64 + ni*16 + lr;
            float bv = bias[col];
#pragma unroll
            for (int j = 0; j < 4; ++j) {
                int row = m0 + wr*64 + mi*16 + lq*4 + j;
                Cp[(size_t)row*DM + col] = (half_t)((acc[mi][ni][j] + bv) * os);
            }
        }
    }
}

// ---------------- deep-pipelined projection GEMM (single-input variants) ----------------
template<bool OUT_F32, bool VEPI>
__global__ __launch_bounds__(512, 2) void proj8_f16(
    const half_t* __restrict__ A, const half_t* __restrict__ Bt,
    const float* __restrict__ bias, float oscale, void* __restrict__ Cp)
{
    __shared__ __align__(16) half_t smem[3 * 24576];
    const int flat = blockIdx.x;                 // 0..255
    const int wg   = (flat & 7) * 32 + (flat >> 3);
    const int n0   = (wg & 3) * 256;
    const int m0   = (wg >> 2) * 128;
    const int t = threadIdx.x, lane = t & 63, wave = t >> 6;
    const int wr = wave >> 2, wc = wave & 3;
    const int lr = lane & 15, lq = lane >> 4;
    const int l7 = lr & 7;

    f32x4 acc[4][4] = {};

#pragma unroll
    for (int kt = 0; kt < 2; ++kt) {
#pragma unroll
        for (int i = 0; i < 2; ++i) {
            int c = i*512 + t, r = c>>3, s = c&7;
            gload16(A + (size_t)(m0 + r)*DM + kt*64 + (s ^ (r&7))*8,
                    smem + kt*24576 + c*8);
        }
#pragma unroll
        for (int i = 0; i < 4; ++i) {
            int c = i*512 + t, r = c>>3, s = c&7;
            gload16(Bt + (size_t)(n0 + r)*DM + kt*64 + (s ^ (r&7))*8,
                    smem + kt*24576 + 8192 + c*8);
        }
    }
    asm volatile("s_waitcnt vmcnt(6)" ::: "memory");
    __builtin_amdgcn_s_barrier();

    for (int kt = 0; kt < 16; ++kt) {
        const int cur = kt % 3;
        const half_t* lA = smem + cur*24576;
        const half_t* lB = smem + cur*24576 + 8192;

        if (kt + 2 < 16) {
            const int nxt = (kt + 2) % 3;
            const int kn = kt + 2;
#pragma unroll
            for (int i = 0; i < 2; ++i) {
                int c = i*512 + t, r = c>>3, s = c&7;
                gload16(A + (size_t)(m0 + r)*DM + kn*64 + (s ^ (r&7))*8,
                        smem + nxt*24576 + c*8);
            }
#pragma unroll
            for (int i = 0; i < 4; ++i) {
                int c = i*512 + t, r = c>>3, s = c&7;
                gload16(Bt + (size_t)(n0 + r)*DM + kn*64 + (s ^ (r&7))*8,
                        smem + nxt*24576 + 8192 + c*8);
            }
        }

        half8 af[4][2], bf[4][2];
#pragma unroll
        for (int mi = 0; mi < 4; ++mi)
#pragma unroll
            for (int kk = 0; kk < 2; ++kk)
                af[mi][kk] = *(const half8*)(lA + (wr*64 + mi*16 + lr)*64 + (((kk*4+lq) ^ l7))*8);
#pragma unroll
        for (int ni = 0; ni < 4; ++ni)
#pragma unroll
            for (int kk = 0; kk < 2; ++kk)
                bf[ni][kk] = *(const half8*)(lB + (wc*64 + ni*16 + lr)*64 + (((kk*4+lq) ^ l7))*8);

        __builtin_amdgcn_s_setprio(1);
#pragma unroll
        for (int mi = 0; mi < 4; ++mi)
#pragma unroll
            for (int ni = 0; ni < 4; ++ni)
#pragma unroll
                for (int kk = 0; kk < 2; ++kk)
                    acc[mi][ni] = __builtin_amdgcn_mfma_f32_16x16x32_f16(af[mi][kk], bf[ni][kk], acc[mi][ni], 0, 0, 0);
        __builtin_amdgcn_s_setprio(0);

        if (kt < 15) {
            if (kt < 14) asm volatile("s_waitcnt vmcnt(6)" ::: "memory");
            else         asm volatile("s_waitcnt vmcnt(0)" ::: "memory");
            __builtin_amdgcn_s_barrier();
        }
    }

    const int b = m0 >> 11;
#pragma unroll
    for (int mi = 0; mi < 4; ++mi) {
#pragma unroll
        for (int ni = 0; ni < 4; ++ni) {
            int col = n0 + wc*64 + ni*16 + lr;
            float bv = bias[col];
            if (VEPI) {
                int rl = (m0 + wr*64 + mi*16 + lq*4) & (SEQ-1);   // %4 == 0
                int pos = (rl & ~63) | (((rl>>5)&1)<<5) | (((rl>>2)&3)<<3) | (((rl>>4)&1)<<2);
                half4 hv;
#pragma unroll
                for (int j = 0; j < 4; ++j)
                    hv[j] = (half_t)(acc[mi][ni][j] + bv);
                *(half4*)((half_t*)Cp + ((size_t)(b*NH*DEPTH + col))*SEQ + pos) = hv;
            } else {
#pragma unroll
                for (int j = 0; j < 4; ++j) {
                    int row = m0 + wr*64 + mi*16 + lq*4 + j;
                    float vv = (acc[mi][ni][j] + bv) * oscale;
                    if (OUT_F32)
                        ((float*)Cp)[(size_t)row*DM + col] = vv;
                    else
                        ((half_t*)Cp)[(size_t)row*DM + col] = (half_t)vv;
                }
            }
        }
    }
}

// ---------------- fused flash attention: KVBLK=128, swizzled K-LDS ----------------
// lK: [128 rows][64 halves], chunk s of row r stored at slot s^(r&7) (T2).
__global__ __launch_bounds__(512, 4) void attn_k(
    const half_t* __restrict__ Qh, const half_t* __restrict__ Kc,
    const half_t* __restrict__ Vt, const int* __restrict__ cnt,
    half_t* __restrict__ Oh)
{
    constexpr int VP = 136;
    __shared__ __align__(16) half_t lK[2][128 * 64];   // 32 KB, swizzled
    __shared__ __align__(16) half_t lV[2][64 * VP];    // 34.8 KB
    const int t = threadIdx.x;
    const int lane = t & 63, wave = t >> 6;
    const int lr = lane & 15, lq = lane >> 4;
    const int flat = blockIdx.x;             // 0..511
    const int rest = flat >> 3;
    const int qb = rest & 7;
    const int bh = (flat & 7) + 8 * (rest >> 3);
    const int b = bh >> 4, h = bh & 15;
    const int q0 = qb * 256;

    const int nc = cnt[b];
    const int ntk = (nc + 127) >> 7;

    const size_t qbase = ((size_t)(b*SEQ + q0 + wave*32 + lr))*DM + h*DEPTH;
    const half8 aq00 = *(const half8*)(Qh + qbase + lq*8);
    const half8 aq01 = *(const half8*)(Qh + qbase + 32 + lq*8);
    const half8 aq10 = *(const half8*)(Qh + qbase + (size_t)16*DM + lq*8);
    const half8 aq11 = *(const half8*)(Qh + qbase + (size_t)16*DM + 32 + lq*8);

    // K staging: thread -> row krow=t>>2, chunks 2a,2a+1 (a=t&3); swizzled slots
    const int krow = t >> 2, ka = t & 3;
    const int kp0 = (2*ka)     ^ (krow & 7);
    const int kp1 = (2*ka + 1) ^ (krow & 7);
    const int vd   = t >> 3, vs   = (t & 7) * 16;
    const half_t* gK = Kc + (size_t)(b*SEQ + krow)*DM + h*DEPTH + ka*16;
    const half_t* gV = Vt + ((size_t)bh*DEPTH + vd)*SEQ + vs;

    f32x4 o[2][4] = {};
    f32x4 ol[2] = {};
    half8 onesv;
#pragma unroll
    for (int e = 0; e < 8; ++e) onesv[e] = (half_t)1.0f;
    const f32x4 minit = {-8.0f, -8.0f, -8.0f, -8.0f};

    half8 kr0 = *(const half8*)gK,     kr1 = *(const half8*)(gK + 8);
    half8 vr0 = *(const half8*)gV,     vr1 = *(const half8*)(gV + 8);
    *(half8*)&lK[0][krow*64 + kp0*8] = kr0;
    *(half8*)&lK[0][krow*64 + kp1*8] = kr1;
    *(half8*)&lV[0][vd*VP + vs]      = vr0;
    *(half8*)&lV[0][vd*VP + vs + 8]  = vr1;
    __syncthreads();

    for (int it = 0; it < ntk; ++it) {
        const int cur = it & 1;
        const int kt = it * 128;
        const bool more = (it + 1 < ntk);
        if (more) {
            const half_t* nk = gK + (size_t)(it+1)*128*DM;
            const half_t* nv = gV + (it+1)*128;
            kr0 = *(const half8*)nk;  kr1 = *(const half8*)(nk + 8);
            vr0 = *(const half8*)nv;  vr1 = *(const half8*)(nv + 8);
        }
        const bool full = (kt + 128 <= nc);

#pragma unroll
        for (int c = 0; c < 4; ++c) {
            f32x4 s[2][2] = {{minit, minit}, {minit, minit}};
            __builtin_amdgcn_s_setprio(1);
#pragma unroll
            for (int cc = 0; cc < 2; ++cc) {
                const half_t* kb = &lK[cur][((2*c+cc)*16 + lr)*64];
                half8 kf0 = *(const half8*)(kb + ((lq     ^ (lr&7)))*8);
                half8 kf1 = *(const half8*)(kb + (((4+lq) ^ (lr&7)))*8);
                s[0][cc] = __builtin_amdgcn_mfma_f32_16x16x32_f16(kf0, aq00, s[0][cc], 0, 0, 0);
                s[0][cc] = __builtin_amdgcn_mfma_f32_16x16x32_f16(kf1, aq01, s[0][cc], 0, 0, 0);
                s[1][cc] = __builtin_amdgcn_mfma_f32_16x16x32_f16(kf0, aq10, s[1][cc], 0, 0, 0);
                s[1][cc] = __builtin_amdgcn_mfma_f32_16x16x32_f16(kf1, aq11, s[1][cc], 0, 0, 0);
            }
            __builtin_amdgcn_s_setprio(0);

            half8 pk0, pk1;
            if (full) {
#pragma unroll
                for (int cc = 0; cc < 2; ++cc)
#pragma unroll
                    for (int r = 0; r < 4; ++r) {
                        pk0[cc*4 + r] = (half_t)__builtin_amdgcn_exp2f(s[0][cc][r]);
                        pk1[cc*4 + r] = (half_t)__builtin_amdgcn_exp2f(s[1][cc][r]);
                    }
            } else {
#pragma unroll
                for (int cc = 0; cc < 2; ++cc)
#pragma unroll
                    for (int r = 0; r < 4; ++r) {
                        float am = (kt + (2*c+cc)*16 + lq*4 + r < nc) ? 0.0f : -1e30f;
                        pk0[cc*4 + r] = (half_t)__builtin_amdgcn_exp2f(s[0][cc][r] + am);
                        pk1[cc*4 + r] = (half_t)__builtin_amdgcn_exp2f(s[1][cc][r] + am);
                    }
            }

            __builtin_amdgcn_s_setprio(1);
#pragma unroll
            for (int ni = 0; ni < 4; ++ni) {
                half8 av = *(const half8*)(&lV[cur][(ni*16 + lr)*VP + c*32 + lq*8]);
                o[0][ni] = __builtin_amdgcn_mfma_f32_16x16x32_f16(av, pk0, o[0][ni], 0, 0, 0);
                o[1][ni] = __builtin_amdgcn_mfma_f32_16x16x32_f16(av, pk1, o[1][ni], 0, 0, 0);
            }
            ol[0] = __builtin_amdgcn_mfma_f32_16x16x32_f16(onesv, pk0, ol[0], 0, 0, 0);
            ol[1] = __builtin_amdgcn_mfma_f32_16x16x32_f16(onesv, pk1, ol[1], 0, 0, 0);
            __builtin_amdgcn_s_setprio(0);
        }

        if (more) {
            *(half8*)&lK[cur^1][krow*64 + kp0*8] = kr0;
            *(half8*)&lK[cur^1][krow*64 + kp1*8] = kr1;
            *(half8*)&lV[cur^1][vd*VP + vs]      = vr0;
            *(half8*)&lV[cur^1][vd*VP + vs + 8]  = vr1;
        }
        __syncthreads();
    }

    // epilogue: per-wave scratch in lK (2x128x64 = 16384 halves = 8 waves x 32 x 64)
    // col-XOR swizzle: logical col c of row r stored at c ^ (8*(r&7))
    half_t* pb = ((half_t*)lK) + wave * 32 * 64;
    float rl0 = 1.0f / ol[0][0];
    float rl1 = 1.0f / ol[1][0];
#pragma unroll
    for (int ni = 0; ni < 4; ++ni)
#pragma unroll
        for (int j = 0; j < 4; ++j) {
            int c = ni*16 + lq*4 + j;
            pb[lr*64        + (c ^ (8*(lr&7)))] = (half_t)(o[0][ni][j] * rl0);
            pb[(16+lr)*64   + (c ^ (8*(lr&7)))] = (half_t)(o[1][ni][j] * rl1);
        }
    __syncthreads();
#pragma unroll
    for (int rr = 0; rr < 4; ++rr) {
        int qq = rr*8 + (lane >> 3);
        int c8 = (lane & 7) * 8;
        half8 hv = *(const half8*)(pb + qq*64 + (c8 ^ (8*(qq&7))));
        *(half8*)(Oh + (size_t)(b*SEQ + q0 + wave*32 + qq)*DM + h*DEPTH + c8) = hv;
    }
}

extern "C" void kernel_launch(void* const* d_in, const int* in_sizes, int n_in,
                              void* d_out, int out_size, void* d_ws, size_t ws_size,
                              hipStream_t stream) {
    (void)in_sizes; (void)n_in; (void)out_size; (void)ws_size;
    const float* v    = (const float*)d_in[0];
    const float* k    = (const float*)d_in[1];
    const float* q    = (const float*)d_in[2];
    const int*   mask = (const int*)  d_in[3];
    const float* wq   = (const float*)d_in[4];
    const float* bq   = (const float*)d_in[5];
    const float* wk   = (const float*)d_in[6];
    const float* bk   = (const float*)d_in[7];
    const float* wv   = (const float*)d_in[8];
    const float* bv   = (const float*)d_in[9];
    const float* wo   = (const float*)d_in[10];
    const float* bo   = (const float*)d_in[11];

    // 72 MB workspace (halves); Qh lives in d_out's front 16 MB.
    half_t* wT  = (half_t*)d_ws;                 //  8 MB: 4 weights f16^T
    half_t* xfq = wT + 4ull*1024*1024;           // 16 MB: q-f16; later Vt
    half_t* xfk = xfq + 8ull*1024*1024;          // 16 MB: k-f16 (gathered)
    half_t* xfv = xfk + 8ull*1024*1024;          // 16 MB: v-f16 (gathered); later O16
    half_t* Kc  = xfv + 8ull*1024*1024;          // 16 MB: compacted K (full-M write)
    half_t* Qh  = (half_t*)d_out;                // alias: d_out front (16 MB)
    half_t* Vt  = xfq;                           // alias (xfq dead after qk8_k)
    half_t* O16 = xfv;                           // alias (xfv dead after vproj)

    // idx/cnt in d_out tail (consumed before o_proj overwrites d_out)
    int* idx = (int*)((char*)d_out + 32ull*1024*1024 - 65536);
    int* cnt = idx + 4*SEQ;

    const float qscale = 0.125f * 1.44269504088896340736f;  // depth^-1/2 * log2(e)

    wm_k<<<dim3(32,32,5), dim3(32,8), 0, stream>>>(wq, wk, wv, wo, wT, mask, idx, cnt);
    cvt3_k<<<5120, 256, 0, stream>>>(q, k, v, idx, cnt, xfq, xfk, xfv);

    qk8_k<<<512, 512, 0, stream>>>(xfq, xfk, wT, bq, bk, qscale, Qh, Kc);
    proj8_f16<false,true><<<256, 512, 0, stream>>>(xfv, wT + 2ull*1024*1024, bv, 1.0f, Vt);

    attn_k<<<512, 512, 0, stream>>>(Qh, Kc, Vt, cnt, O16);
    proj8_f16<true,false><<<256, 512, 0, stream>>>(O16, wT + 3ull*1024*1024, bo, 1.0f, (float*)d_out);
}

// Round 23
// 164.958 us; speedup vs baseline: 1.0312x; 1.0312x over previous
//
#include <hip/hip_runtime.h>

typedef _Float16 half_t;
typedef __attribute__((ext_vector_type(8))) _Float16 half8;
typedef __attribute__((ext_vector_type(4))) _Float16 half4;
typedef __attribute__((ext_vector_type(4))) float f32x4;

#define SEQ   2048
#define DM    1024
#define NH    16
#define DEPTH 64

__device__ __forceinline__ void gload16(const void* g, void* l) {
    __builtin_amdgcn_global_load_lds(
        (const __attribute__((address_space(1))) void*)g,
        (__attribute__((address_space(3))) void*)l, 16, 0, 0);
}

// ---------------- weight transpose + fp32->fp16  AND  mask compaction ----------------
__global__ __launch_bounds__(256) void wm_k(
    const float* __restrict__ w0, const float* __restrict__ w1,
    const float* __restrict__ w2, const float* __restrict__ w3,
    half_t* __restrict__ out,
    const int* __restrict__ mask, int* __restrict__ idx, int* __restrict__ cnt)
{
    const int z = blockIdx.z;
    if (z == 4) {
        if (blockIdx.x || blockIdx.y) return;
        const int tid = threadIdx.y * 32 + threadIdx.x;
        const int b = tid >> 6;
        const int lane = tid & 63;
        const int* m = mask + b*SEQ;
        int* ib = idx + b*SEQ;
        int off = 0;
        for (int c = 0; c < SEQ; c += 64) {
            int keep = (m[c + lane] == 0);
            unsigned long long bal = __ballot(keep);
            int pre = __popcll(bal & ((1ull << lane) - 1ull));
            if (keep) ib[off + pre] = c + lane;
            off += __popcll(bal);
        }
        if (lane == 0) cnt[b] = off;
        return;
    }
    __shared__ float tile[32][33];
    const float* srcs[4] = {w0, w1, w2, w3};
    const float* src = srcs[z];
    half_t* dst = out + (size_t)z * DM * DM;
    int n0 = blockIdx.x * 32, k0 = blockIdx.y * 32;
    int tx = threadIdx.x, ty = threadIdx.y;
#pragma unroll
    for (int i = 0; i < 4; ++i)
        tile[ty + 8*i][tx] = src[(size_t)(k0 + ty + 8*i)*DM + n0 + tx];
    __syncthreads();
#pragma unroll
    for (int i = 0; i < 4; ++i)
        dst[(size_t)(n0 + ty + 8*i)*DM + k0 + tx] = (half_t)tile[tx][ty + 8*i];
}

// ---------------- q convert + k/v gather-convert, one launch ----------------
__global__ __launch_bounds__(256) void cvt3_k(
    const float* __restrict__ qsrc, const float* __restrict__ ksrc,
    const float* __restrict__ vsrc,
    const int* __restrict__ idx, const int* __restrict__ cnt,
    half_t* __restrict__ qdst, half_t* __restrict__ kdst, half_t* __restrict__ vdst)
{
    const int bid = blockIdx.x;
    const int t = threadIdx.x;
    if (bid < 4096) {
        size_t i = ((size_t)bid * 256 + t) * 8;
        float4 a = *(const float4*)(qsrc + i);
        float4 b = *(const float4*)(qsrc + i + 4);
        half8 h;
        h[0]=(half_t)a.x; h[1]=(half_t)a.y; h[2]=(half_t)a.z; h[3]=(half_t)a.w;
        h[4]=(half_t)b.x; h[5]=(half_t)b.y; h[6]=(half_t)b.z; h[7]=(half_t)b.w;
        *(half8*)(qdst + i) = h;
        return;
    }
    const int which = (bid >= 4608);
    const float* src = which ? vsrc : ksrc;
    half_t*      dst = which ? vdst : kdst;
    const int r0 = (bid - (which ? 4608 : 4096)) * 16;
    const int b  = r0 >> 11;
    const int nc = cnt[b];
    const int row = r0 + (t >> 4);
    const int jl  = row & (SEQ - 1);
    if (jl >= nc) return;
    const float* sp = src + (size_t)((b << 11) + idx[(b << 11) + jl]) * DM;
    half_t* dp = dst + (size_t)row * DM;
#pragma unroll
    for (int i = 0; i < 8; ++i) {
        int c = i*128 + (t & 15)*8;
        float4 lo = *(const float4*)(sp + c);
        float4 hi = *(const float4*)(sp + c + 4);
        half8 h;
        h[0]=(half_t)lo.x; h[1]=(half_t)lo.y; h[2]=(half_t)lo.z; h[3]=(half_t)lo.w;
        h[4]=(half_t)hi.x; h[5]=(half_t)hi.y; h[6]=(half_t)hi.z; h[7]=(half_t)hi.w;
        *(half8*)(dp + c) = h;
    }
}

// LDS XOR-swizzle (T2, rule #21): LDS[r][s] holds global slot s^(r&7).
// gload dest stays linear; source pre-swizzled; reads XOR the same way.

// ---------------- merged Q+K deep-pipelined projection (512 blocks, z-decode) ----------------
__global__ __launch_bounds__(512, 2) void qk8_k(
    const half_t* __restrict__ Aq, const half_t* __restrict__ Ak,
    const half_t* __restrict__ wT,
    const float* __restrict__ bq, const float* __restrict__ bk,
    float qscale,
    half_t* __restrict__ Qh, half_t* __restrict__ Kc)
{
    __shared__ __align__(16) half_t smem[3 * 24576];
    const int flat = blockIdx.x;                 // 0..511
    const int wg   = (flat & 7) * 64 + (flat >> 3);
    const int z    = wg >> 8;                    // 0=Q, 1=K
    const int rem  = wg & 255;
    const int n0   = (rem & 3) * 256;
    const int m0   = (rem >> 2) * 128;

    const half_t* A    = z ? Ak : Aq;
    const half_t* Bt   = wT + (size_t)z * DM * DM;
    const float*  bias = z ? bk : bq;
    half_t*       Cp   = z ? Kc : Qh;
    const float   os   = z ? 1.0f : qscale;

    const int t = threadIdx.x, lane = t & 63, wave = t >> 6;
    const int wr = wave >> 2, wc = wave & 3;
    const int lr = lane & 15, lq = lane >> 4;
    const int l7 = lr & 7;

    f32x4 acc[4][4] = {};

#pragma unroll
    for (int kt = 0; kt < 2; ++kt) {
#pragma unroll
        for (int i = 0; i < 2; ++i) {
            int c = i*512 + t, r = c>>3, s = c&7;
            gload16(A + (size_t)(m0 + r)*DM + kt*64 + (s ^ (r&7))*8,
                    smem + kt*24576 + c*8);
        }
#pragma unroll
        for (int i = 0; i < 4; ++i) {
            int c = i*512 + t, r = c>>3, s = c&7;
            gload16(Bt + (size_t)(n0 + r)*DM + kt*64 + (s ^ (r&7))*8,
                    smem + kt*24576 + 8192 + c*8);
        }
    }
    asm volatile("s_waitcnt vmcnt(6)" ::: "memory");
    __builtin_amdgcn_s_barrier();

    for (int kt = 0; kt < 16; ++kt) {
        const int cur = kt % 3;
        const half_t* lA = smem + cur*24576;
        const half_t* lB = smem + cur*24576 + 8192;

        half8 af[4][2], bf[4][2];
#pragma unroll
        for (int mi = 0; mi < 4; ++mi)
#pragma unroll
            for (int kk = 0; kk < 2; ++kk)
                af[mi][kk] = *(const half8*)(lA + (wr*64 + mi*16 + lr)*64 + (((kk*4+lq) ^ l7))*8);
#pragma unroll
        for (int ni = 0; ni < 4; ++ni)
#pragma unroll
            for (int kk = 0; kk < 2; ++kk)
                bf[ni][kk] = *(const half8*)(lB + (wc*64 + ni*16 + lr)*64 + (((kk*4+lq) ^ l7))*8);

        if (kt + 2 < 16) {
            const int nxt = (kt + 2) % 3;
            const int kn = kt + 2;
#pragma unroll
            for (int i = 0; i < 2; ++i) {
                int c = i*512 + t, r = c>>3, s = c&7;
                gload16(A + (size_t)(m0 + r)*DM + kn*64 + (s ^ (r&7))*8,
                        smem + nxt*24576 + c*8);
            }
#pragma unroll
            for (int i = 0; i < 4; ++i) {
                int c = i*512 + t, r = c>>3, s = c&7;
                gload16(Bt + (size_t)(n0 + r)*DM + kn*64 + (s ^ (r&7))*8,
                        smem + nxt*24576 + 8192 + c*8);
            }
        }

        __builtin_amdgcn_s_setprio(1);
#pragma unroll
        for (int mi = 0; mi < 4; ++mi)
#pragma unroll
            for (int ni = 0; ni < 4; ++ni)
#pragma unroll
                for (int kk = 0; kk < 2; ++kk)
                    acc[mi][ni] = __builtin_amdgcn_mfma_f32_16x16x32_f16(af[mi][kk], bf[ni][kk], acc[mi][ni], 0, 0, 0);
        __builtin_amdgcn_s_setprio(0);

        if (kt < 15) {
            if (kt < 14) asm volatile("s_waitcnt vmcnt(6)" ::: "memory");
            else         asm volatile("s_waitcnt vmcnt(0)" ::: "memory");
            __builtin_amdgcn_s_barrier();
        }
    }

#pragma unroll
    for (int mi = 0; mi < 4; ++mi) {
#pragma unroll
        for (int ni = 0; ni < 4; ++ni) {
            int col = n0 + wc*64 + ni*16 + lr;
            float bv = bias[col];
#pragma unroll
            for (int j = 0; j < 4; ++j) {
                int row = m0 + wr*64 + mi*16 + lq*4 + j;
                Cp[(size_t)row*DM + col] = (half_t)((acc[mi][ni][j] + bv) * os);
            }
        }
    }
}

// ---------------- deep-pipelined projection GEMM (single-input variants) ----------------
template<bool OUT_F32, bool VEPI>
__global__ __launch_bounds__(512, 2) void proj8_f16(
    const half_t* __restrict__ A, const half_t* __restrict__ Bt,
    const float* __restrict__ bias, float oscale, void* __restrict__ Cp)
{
    __shared__ __align__(16) half_t smem[3 * 24576];
    const int flat = blockIdx.x;                 // 0..255
    const int wg   = (flat & 7) * 32 + (flat >> 3);
    const int n0   = (wg & 3) * 256;
    const int m0   = (wg >> 2) * 128;
    const int t = threadIdx.x, lane = t & 63, wave = t >> 6;
    const int wr = wave >> 2, wc = wave & 3;
    const int lr = lane & 15, lq = lane >> 4;
    const int l7 = lr & 7;

    f32x4 acc[4][4] = {};

#pragma unroll
    for (int kt = 0; kt < 2; ++kt) {
#pragma unroll
        for (int i = 0; i < 2; ++i) {
            int c = i*512 + t, r = c>>3, s = c&7;
            gload16(A + (size_t)(m0 + r)*DM + kt*64 + (s ^ (r&7))*8,
                    smem + kt*24576 + c*8);
        }
#pragma unroll
        for (int i = 0; i < 4; ++i) {
            int c = i*512 + t, r = c>>3, s = c&7;
            gload16(Bt + (size_t)(n0 + r)*DM + kt*64 + (s ^ (r&7))*8,
                    smem + kt*24576 + 8192 + c*8);
        }
    }
    asm volatile("s_waitcnt vmcnt(6)" ::: "memory");
    __builtin_amdgcn_s_barrier();

    for (int kt = 0; kt < 16; ++kt) {
        const int cur = kt % 3;
        const half_t* lA = smem + cur*24576;
        const half_t* lB = smem + cur*24576 + 8192;

        half8 af[4][2], bf[4][2];
#pragma unroll
        for (int mi = 0; mi < 4; ++mi)
#pragma unroll
            for (int kk = 0; kk < 2; ++kk)
                af[mi][kk] = *(const half8*)(lA + (wr*64 + mi*16 + lr)*64 + (((kk*4+lq) ^ l7))*8);
#pragma unroll
        for (int ni = 0; ni < 4; ++ni)
#pragma unroll
            for (int kk = 0; kk < 2; ++kk)
                bf[ni][kk] = *(const half8*)(lB + (wc*64 + ni*16 + lr)*64 + (((kk*4+lq) ^ l7))*8);

        if (kt + 2 < 16) {
            const int nxt = (kt + 2) % 3;
            const int kn = kt + 2;
#pragma unroll
            for (int i = 0; i < 2; ++i) {
                int c = i*512 + t, r = c>>3, s = c&7;
                gload16(A + (size_t)(m0 + r)*DM + kn*64 + (s ^ (r&7))*8,
                        smem + nxt*24576 + c*8);
            }
#pragma unroll
            for (int i = 0; i < 4; ++i) {
                int c = i*512 + t, r = c>>3, s = c&7;
                gload16(Bt + (size_t)(n0 + r)*DM + kn*64 + (s ^ (r&7))*8,
                        smem + nxt*24576 + 8192 + c*8);
            }
        }

        __builtin_amdgcn_s_setprio(1);
#pragma unroll
        for (int mi = 0; mi < 4; ++mi)
#pragma unroll
            for (int ni = 0; ni < 4; ++ni)
#pragma unroll
                for (int kk = 0; kk < 2; ++kk)
                    acc[mi][ni] = __builtin_amdgcn_mfma_f32_16x16x32_f16(af[mi][kk], bf[ni][kk], acc[mi][ni], 0, 0, 0);
        __builtin_amdgcn_s_setprio(0);

        if (kt < 15) {
            if (kt < 14) asm volatile("s_waitcnt vmcnt(6)" ::: "memory");
            else         asm volatile("s_waitcnt vmcnt(0)" ::: "memory");
            __builtin_amdgcn_s_barrier();
        }
    }

    const int b = m0 >> 11;
#pragma unroll
    for (int mi = 0; mi < 4; ++mi) {
#pragma unroll
        for (int ni = 0; ni < 4; ++ni) {
            int col = n0 + wc*64 + ni*16 + lr;
            float bv = bias[col];
            if (VEPI) {
                int rl = (m0 + wr*64 + mi*16 + lq*4) & (SEQ-1);   // %4 == 0
                int pos = (rl & ~63) | (((rl>>5)&1)<<5) | (((rl>>2)&3)<<3) | (((rl>>4)&1)<<2);
                half4 hv;
#pragma unroll
                for (int j = 0; j < 4; ++j)
                    hv[j] = (half_t)(acc[mi][ni][j] + bv);
                *(half4*)((half_t*)Cp + ((size_t)(b*NH*DEPTH + col))*SEQ + pos) = hv;
            } else {
#pragma unroll
                for (int j = 0; j < 4; ++j) {
                    int row = m0 + wr*64 + mi*16 + lq*4 + j;
                    float vv = (acc[mi][ni][j] + bv) * oscale;
                    if (OUT_F32)
                        ((float*)Cp)[(size_t)row*DM + col] = vv;
                    else
                        ((half_t*)Cp)[(size_t)row*DM + col] = (half_t)vv;
                }
            }
        }
    }
}

// ---------------- fused flash attention: KVBLK=128, streamed 32-key chunks ----------------
__global__ __launch_bounds__(512, 4) void attn_k(
    const half_t* __restrict__ Qh, const half_t* __restrict__ Kc,
    const half_t* __restrict__ Vt, const int* __restrict__ cnt,
    half_t* __restrict__ Oh)
{
    constexpr int KP = 72;
    constexpr int VP = 136;
    __shared__ __align__(16) half_t lK[2][128 * KP];
    __shared__ __align__(16) half_t lV[2][64 * VP];
    const int t = threadIdx.x;
    const int lane = t & 63, wave = t >> 6;
    const int lr = lane & 15, lq = lane >> 4;
    const int flat = blockIdx.x;             // 0..511
    const int rest = flat >> 3;
    const int qb = rest & 7;
    const int bh = (flat & 7) + 8 * (rest >> 3);
    const int b = bh >> 4, h = bh & 15;
    const int q0 = qb * 256;

    const int nc = cnt[b];
    const int ntk = (nc + 127) >> 7;

    const size_t qbase = ((size_t)(b*SEQ + q0 + wave*32 + lr))*DM + h*DEPTH;
    const half8 aq00 = *(const half8*)(Qh + qbase + lq*8);
    const half8 aq01 = *(const half8*)(Qh + qbase + 32 + lq*8);
    const half8 aq10 = *(const half8*)(Qh + qbase + (size_t)16*DM + lq*8);
    const half8 aq11 = *(const half8*)(Qh + qbase + (size_t)16*DM + 32 + lq*8);

    const int krow = t >> 2, kcol = (t & 3) * 16;
    const int vd   = t >> 3, vs   = (t & 7) * 16;
    const half_t* gK = Kc + (size_t)(b*SEQ + krow)*DM + h*DEPTH + kcol;
    const half_t* gV = Vt + ((size_t)bh*DEPTH + vd)*SEQ + vs;

    f32x4 o[2][4] = {};
    f32x4 ol[2] = {};
    half8 onesv;
#pragma unroll
    for (int e = 0; e < 8; ++e) onesv[e] = (half_t)1.0f;
    const f32x4 minit = {-8.0f, -8.0f, -8.0f, -8.0f};

    half8 kr0 = *(const half8*)gK,       kr1 = *(const half8*)(gK + 8);
    half8 vr0 = *(const half8*)gV,       vr1 = *(const half8*)(gV + 8);
    *(half8*)&lK[0][krow*KP + kcol]     = kr0;
    *(half8*)&lK[0][krow*KP + kcol + 8] = kr1;
    *(half8*)&lV[0][vd*VP + vs]         = vr0;
    *(half8*)&lV[0][vd*VP + vs + 8]     = vr1;
    __syncthreads();

    for (int it = 0; it < ntk; ++it) {
        const int cur = it & 1;
        const int kt = it * 128;
        const bool more = (it + 1 < ntk);
        if (more) {
            const half_t* nk = gK + (size_t)(it+1)*128*DM;
            const half_t* nv = gV + (it+1)*128;
            kr0 = *(const half8*)nk;  kr1 = *(const half8*)(nk + 8);
            vr0 = *(const half8*)nv;  vr1 = *(const half8*)(nv + 8);
        }
        const bool full = (kt + 128 <= nc);

#pragma unroll
        for (int c = 0; c < 4; ++c) {
            f32x4 s[2][2] = {{minit, minit}, {minit, minit}};
            __builtin_amdgcn_s_setprio(1);
#pragma unroll
            for (int cc = 0; cc < 2; ++cc) {
                const half_t* kb = &lK[cur][((2*c+cc)*16 + lr)*KP];
                half8 kf0 = *(const half8*)(kb + lq*8);
                half8 kf1 = *(const half8*)(kb + 32 + lq*8);
                s[0][cc] = __builtin_amdgcn_mfma_f32_16x16x32_f16(kf0, aq00, s[0][cc], 0, 0, 0);
                s[0][cc] = __builtin_amdgcn_mfma_f32_16x16x32_f16(kf1, aq01, s[0][cc], 0, 0, 0);
                s[1][cc] = __builtin_amdgcn_mfma_f32_16x16x32_f16(kf0, aq10, s[1][cc], 0, 0, 0);
                s[1][cc] = __builtin_amdgcn_mfma_f32_16x16x32_f16(kf1, aq11, s[1][cc], 0, 0, 0);
            }
            __builtin_amdgcn_s_setprio(0);

            half8 pk0, pk1;
            if (full) {
#pragma unroll
                for (int cc = 0; cc < 2; ++cc)
#pragma unroll
                    for (int r = 0; r < 4; ++r) {
                        pk0[cc*4 + r] = (half_t)__builtin_amdgcn_exp2f(s[0][cc][r]);
                        pk1[cc*4 + r] = (half_t)__builtin_amdgcn_exp2f(s[1][cc][r]);
                    }
            } else {
#pragma unroll
                for (int cc = 0; cc < 2; ++cc)
#pragma unroll
                    for (int r = 0; r < 4; ++r) {
                        float am = (kt + (2*c+cc)*16 + lq*4 + r < nc) ? 0.0f : -1e30f;
                        pk0[cc*4 + r] = (half_t)__builtin_amdgcn_exp2f(s[0][cc][r] + am);
                        pk1[cc*4 + r] = (half_t)__builtin_amdgcn_exp2f(s[1][cc][r] + am);
                    }
            }

            __builtin_amdgcn_s_setprio(1);
#pragma unroll
            for (int ni = 0; ni < 4; ++ni) {
                half8 av = *(const half8*)(&lV[cur][(ni*16 + lr)*VP + c*32 + lq*8]);
                o[0][ni] = __builtin_amdgcn_mfma_f32_16x16x32_f16(av, pk0, o[0][ni], 0, 0, 0);
                o[1][ni] = __builtin_amdgcn_mfma_f32_16x16x32_f16(av, pk1, o[1][ni], 0, 0, 0);
            }
            ol[0] = __builtin_amdgcn_mfma_f32_16x16x32_f16(onesv, pk0, ol[0], 0, 0, 0);
            ol[1] = __builtin_amdgcn_mfma_f32_16x16x32_f16(onesv, pk1, ol[1], 0, 0, 0);
            __builtin_amdgcn_s_setprio(0);
        }

        if (more) {
            *(half8*)&lK[cur^1][krow*KP + kcol]     = kr0;
            *(half8*)&lK[cur^1][krow*KP + kcol + 8] = kr1;
            *(half8*)&lV[cur^1][vd*VP + vs]         = vr0;
            *(half8*)&lV[cur^1][vd*VP + vs + 8]     = vr1;
        }
        __syncthreads();
    }

    half_t* pb = ((half_t*)lK) + wave * 32 * KP;
    float rl0 = 1.0f / ol[0][0];
    float rl1 = 1.0f / ol[1][0];
#pragma unroll
    for (int ni = 0; ni < 4; ++ni)
#pragma unroll
        for (int j = 0; j < 4; ++j) {
            pb[lr*KP + ni*16 + lq*4 + j]        = (half_t)(o[0][ni][j] * rl0);
            pb[(16 + lr)*KP + ni*16 + lq*4 + j] = (half_t)(o[1][ni][j] * rl1);
        }
    __syncthreads();
#pragma unroll
    for (int rr = 0; rr < 4; ++rr) {
        int qq = rr*8 + (lane >> 3);
        int c = (lane & 7) * 8;
        half8 hv = *(const half8*)(pb + qq*KP + c);
        *(half8*)(Oh + (size_t)(b*SEQ + q0 + wave*32 + qq)*DM + h*DEPTH + c) = hv;
    }
}

extern "C" void kernel_launch(void* const* d_in, const int* in_sizes, int n_in,
                              void* d_out, int out_size, void* d_ws, size_t ws_size,
                              hipStream_t stream) {
    (void)in_sizes; (void)n_in; (void)out_size; (void)ws_size;
    const float* v    = (const float*)d_in[0];
    const float* k    = (const float*)d_in[1];
    const float* q    = (const float*)d_in[2];
    const int*   mask = (const int*)  d_in[3];
    const float* wq   = (const float*)d_in[4];
    const float* bq   = (const float*)d_in[5];
    const float* wk   = (const float*)d_in[6];
    const float* bk   = (const float*)d_in[7];
    const float* wv   = (const float*)d_in[8];
    const float* bv   = (const float*)d_in[9];
    const float* wo   = (const float*)d_in[10];
    const float* bo   = (const float*)d_in[11];

    // 72 MB workspace (halves); Qh lives in d_out's front 16 MB.
    half_t* wT  = (half_t*)d_ws;                 //  8 MB: 4 weights f16^T
    half_t* xfq = wT + 4ull*1024*1024;           // 16 MB: q-f16; later Vt
    half_t* xfk = xfq + 8ull*1024*1024;          // 16 MB: k-f16 (gathered)
    half_t* xfv = xfk + 8ull*1024*1024;          // 16 MB: v-f16 (gathered); later O16
    half_t* Kc  = xfv + 8ull*1024*1024;          // 16 MB: compacted K (full-M write)
    half_t* Qh  = (half_t*)d_out;                // alias: d_out front (16 MB)
    half_t* Vt  = xfq;                           // alias (xfq dead after qk8_k)
    half_t* O16 = xfv;                           // alias (xfv dead after vproj)

    // idx/cnt in d_out tail (consumed before o_proj overwrites d_out)
    int* idx = (int*)((char*)d_out + 32ull*1024*1024 - 65536);
    int* cnt = idx + 4*SEQ;

    const float qscale = 0.125f * 1.44269504088896340736f;  // depth^-1/2 * log2(e)

    wm_k<<<dim3(32,32,5), dim3(32,8), 0, stream>>>(wq, wk, wv, wo, wT, mask, idx, cnt);
    cvt3_k<<<5120, 256, 0, stream>>>(q, k, v, idx, cnt, xfq, xfk, xfv);

    qk8_k<<<512, 512, 0, stream>>>(xfq, xfk, wT, bq, bk, qscale, Qh, Kc);
    proj8_f16<false,true><<<256, 512, 0, stream>>>(xfv, wT + 2ull*1024*1024, bv, 1.0f, Vt);

    attn_k<<<512, 512, 0, stream>>>(Qh, Kc, Vt, cnt, O16);
    proj8_f16<true,false><<<256, 512, 0, stream>>>(O16, wT + 3ull*1024*1024, bo, 1.0f, (float*)d_out);
}